// Round 1
// baseline (68.227 us; speedup 1.0000x reference)
//
#include <hip/hip_runtime.h>
#include <math.h>

#define H 128
#define MUL 32
#define NC (5 * MUL * MUL)   // 5120 columns of R
#define DD (4 * MUL)         // 128 output dim
#define NIV (H + 1)          // max intervals = 129
#define NMAX 4000

// Static device scratch (no hipMalloc, no d_ws dependency). Recomputed every launch.
__device__ float g_bp[H];            // sorted breakpoints (invalid = +huge)
__device__ int   g_nbp;              // number of valid breakpoints
__device__ float g_rmid[NIV];        // representative radius per interval
__device__ float g_A[NIV * NC];      // R = rad*A + B per interval
__device__ float g_B[NIV * NC];
__device__ float4 g_ey[NMAX];        // (Y0,Y1,Y2, radius)
__device__ int    g_eidx[NMAX];      // interval index, -1 => fallback (kernel2)

// ---------------- P1: breakpoints, sort, interval midpoints ----------------
__global__ void prep_bp(const float* __restrict__ W1, const float* __restrict__ b1) {
    __shared__ float bp[H];
    __shared__ float sorted[H];
    int k = threadIdx.x;             // blockDim = 128
    float a = W1[k], b = b1[k];
    float v = 3.0e38f;               // invalid sentinel
    if (a != 0.0f) {
        float t = -b / a;
        if (t > 0.0f) v = t;         // only breakpoints in (0, inf) matter (radius >= 0)
    }
    bp[k] = v;
    __syncthreads();
    int rank = 0, nv = 0;
    #pragma unroll 8
    for (int j = 0; j < H; ++j) {
        float bj = bp[j];
        rank += (bj < v) || (bj == v && j < k);
        nv   += (bj < 3.0e38f);
    }
    sorted[rank] = v;
    __syncthreads();
    g_bp[k] = sorted[k];
    if (k == 0) g_nbp = nv;
    int nbp = nv;
    for (int i = k; i <= H; i += H) {   // i = k, and i = 128 for k==0
        float rm;
        if (nbp == 0)       rm = 1.0f;
        else if (i == 0)    rm = 0.5f * sorted[0];
        else if (i >= nbp)  rm = sorted[nbp - 1] + 1.0f;
        else                rm = 0.5f * (sorted[i - 1] + sorted[i]);
        g_rmid[i] = rm;
    }
}

// ---------------- P1b: per-edge radius / Y1 / mask / interval index ----------------
__global__ void prep_edges(const float* __restrict__ r, int N) {
    int n = blockIdx.x * blockDim.x + threadIdx.x;
    if (n >= N) return;
    float x = r[3 * n], y = r[3 * n + 1], z = r[3 * n + 2];
    float rad = sqrtf(x * x + y * y + z * z);
    bool mask = rad > 0.1f;
    float inv = mask ? (1.7320508075688772f / rad) : 0.0f;   // sqrt(3)/rad
    g_ey[n] = make_float4(x * inv, y * inv, z * inv, rad);
    int idx = -1;
    if (mask) {
        int nbp = g_nbp;
        idx = 0;
        for (int j = 0; j < nbp; ++j) idx += (g_bp[j] < rad) ? 1 : 0;
    }
    g_eidx[n] = idx;
}

// ---------------- P2: per-interval rank-1 tables A,B ----------------
__global__ __launch_bounds__(256) void prep_tab(const float* __restrict__ W1,
                                                const float* __restrict__ b1,
                                                const float* __restrict__ W2,
                                                const float* __restrict__ b2) {
    int i = blockIdx.y;
    if (i > g_nbp) return;          // unused intervals: skip (content data-dep, grid fixed)
    int c = blockIdx.x * 256 + threadIdx.x;
    float rm = g_rmid[i];
    float accA = 0.0f, accB = 0.0f;
    #pragma unroll 4
    for (int k = 0; k < H; ++k) {
        float a = W1[k], b = b1[k];
        float w2 = W2[k * NC + c];
        bool act = (a * rm + b) > 0.0f;       // matches relu gate for any radius in interval i
        accA += act ? a * w2 : 0.0f;
        accB += act ? b * w2 : 0.0f;
    }
    g_A[i * NC + c] = accA;
    g_B[i * NC + c] = accB + b2[c];
}

// ---------------- Main: scatter CG kernel blocks, 1 thread per (edge, w, u) ----------------
__global__ __launch_bounds__(256) void main_kernel(const float* __restrict__ lin_w0,
                                                   const float* __restrict__ lin_w1,
                                                   float* __restrict__ out, int N) {
    int bid   = blockIdx.x;
    int wuBlk = bid & 15;            // 16 chunks of 64 wu-pairs (1024 total)
    int eBlk  = bid >> 4;            // edge chunk of 4
    int tx = threadIdx.x & 63;
    int tz = threadIdx.x >> 6;
    int n  = eBlk * 4 + tz;
    if (n >= N) return;
    int wu = wuBlk * 64 + tx;
    int w = wu >> 5, u = wu & 31;

    float* o = out + (size_t)n * (DD * DD);
    int row1 = MUL + 3 * w;          // l=1 output row base
    int col1 = MUL + 3 * u;          // l=1 output col base
    int idx = g_eidx[n];

    if (idx >= 0) {
        float4 ey = g_ey[n];
        float rad = ey.w;
        const float* Arow = g_A + (size_t)idx * NC;
        const float* Brow = g_B + (size_t)idx * NC;
        float acc[5];
        #pragma unroll
        for (int p = 0; p < 5; ++p) {
            int c = p * (MUL * MUL) + wu;
            acc[p] = rad * Arow[c] + Brow[c];    // R[n, p, w, u]
        }
        const float n0   = 0.125f;                  // 1/sqrt(2*MUL)
        const float n1   = 0.10206207261596575f;    // 1/sqrt(3*MUL)
        const float n0s3 = 0.07216878364870323f;    // n0/sqrt(3)
        const float n1s2 = 0.07216878364870323f;    // n1/sqrt(2)  (== n0/sqrt3, exact)
        float Y0 = ey.x, Y1 = ey.y, Y2 = ey.z;

        // K00: out[w, u]
        o[w * DD + u] = n0 * acc[0];
        // K01 (R1b, path 3): out[w, MUL + 3u + i]
        float v3 = n0s3 * acc[3];
        o[w * DD + col1 + 0] = v3 * Y0;
        o[w * DD + col1 + 1] = v3 * Y1;
        o[w * DD + col1 + 2] = v3 * Y2;
        // K10 (R1a, path 2): out[MUL + 3w + j, u]
        float v2 = n1 * acc[2];
        o[(row1 + 0) * DD + u] = v2 * Y0;
        o[(row1 + 1) * DD + u] = v2 * Y1;
        o[(row1 + 2) * DD + u] = v2 * Y2;
        // K11: out[MUL+3w+j, MUL+3u+i] = n1*(R0b*delta_ji) + (n1/sqrt2)*R1c*E[j][i]
        // E = [[0, Y2, -Y1], [-Y2, 0, Y0], [Y1, -Y0, 0]]
        float d = n1 * acc[1];
        float e = n1s2 * acc[4];
        float eY0 = e * Y0, eY1 = e * Y1, eY2 = e * Y2;
        o[(row1 + 0) * DD + col1 + 0] = d;
        o[(row1 + 0) * DD + col1 + 1] = eY2;
        o[(row1 + 0) * DD + col1 + 2] = -eY1;
        o[(row1 + 1) * DD + col1 + 0] = -eY2;
        o[(row1 + 1) * DD + col1 + 1] = d;
        o[(row1 + 1) * DD + col1 + 2] = eY0;
        o[(row1 + 2) * DD + col1 + 0] = eY1;
        o[(row1 + 2) * DD + col1 + 1] = -eY0;
        o[(row1 + 2) * DD + col1 + 2] = d;
    } else {
        // fallback KernelLinear: block-diag, scaled 1/sqrt(MUL)
        const float s = 0.17677669529663687f;
        float v0 = s * lin_w0[w * MUL + u];
        float v1 = s * lin_w1[w * MUL + u];
        o[w * DD + u] = v0;
        o[w * DD + col1 + 0] = 0.0f;
        o[w * DD + col1 + 1] = 0.0f;
        o[w * DD + col1 + 2] = 0.0f;
        o[(row1 + 0) * DD + u] = 0.0f;
        o[(row1 + 1) * DD + u] = 0.0f;
        o[(row1 + 2) * DD + u] = 0.0f;
        o[(row1 + 0) * DD + col1 + 0] = v1;
        o[(row1 + 0) * DD + col1 + 1] = 0.0f;
        o[(row1 + 0) * DD + col1 + 2] = 0.0f;
        o[(row1 + 1) * DD + col1 + 0] = 0.0f;
        o[(row1 + 1) * DD + col1 + 1] = v1;
        o[(row1 + 1) * DD + col1 + 2] = 0.0f;
        o[(row1 + 2) * DD + col1 + 0] = 0.0f;
        o[(row1 + 2) * DD + col1 + 1] = 0.0f;
        o[(row1 + 2) * DD + col1 + 2] = v1;
    }
}

extern "C" void kernel_launch(void* const* d_in, const int* in_sizes, int n_in,
                              void* d_out, int out_size, void* d_ws, size_t ws_size,
                              hipStream_t stream) {
    const float* r   = (const float*)d_in[0];
    const float* W1  = (const float*)d_in[1];
    const float* b1  = (const float*)d_in[2];
    const float* W2  = (const float*)d_in[3];
    const float* b2  = (const float*)d_in[4];
    const float* lw0 = (const float*)d_in[5];
    const float* lw1 = (const float*)d_in[6];
    float* out = (float*)d_out;
    int N = in_sizes[0] / 3;

    prep_bp<<<dim3(1), dim3(H), 0, stream>>>(W1, b1);
    prep_edges<<<dim3((N + 255) / 256), dim3(256), 0, stream>>>(r, N);
    prep_tab<<<dim3(NC / 256, NIV), dim3(256), 0, stream>>>(W1, b1, W2, b2);
    int eChunks = (N + 3) / 4;
    main_kernel<<<dim3(eChunks * 16), dim3(256), 0, stream>>>(lw0, lw1, out, N);
}